// Round 6
// baseline (10206.070 us; speedup 1.0000x reference)
//
#include <hip/hip_runtime.h>

// ============================================================================
// 2-layer LSTM (B=256, T=1024, H=512, in=1) + linear head. fp32 in/out.
//
// R10 (from R9 @10.15ms): attack flag-LINE write serialization.
// R9 (leader poll + x4 replicas + sleep1) was neutral -> read fan-in was not
// the cost. Remaining suspect: all flags of a chunk packed in ONE 128B LLC
// line; 64 producer stores/step + polls serialize on 4 hot lines.
//  1. Flag-per-line: flag[c][sl][rep] each on its OWN 128B line. Producer
//     stores hit 4 private lines; consumer poll = one 64-lane vector read
//     across distinct lines (parallel at LLC, no write queue in front).
//  2. Per-wave independent polling again (drop leader+syncthreads at step
//     start -> one less barrier wake; waves proceed straight to A-loads).
//  3. L1 runahead gate from a FRESH flag view: step-start vector read covers
//     qf (lanes 0-31, blocking) AND pf (lanes 32-47, advisory) -> 'early'
//     (p-loads before phase 1) triggers most steps, not rarely.
// Frozen (R7-verified): slice-major transport + full-line coop st8 stores,
// reg-preloaded A, epoch buffer_inv sc1, deferred head atomic, math
// bit-identical (absmax 6.1e-5).
// Predicted: line-serialization-bound -> 7-8.5ms; flat -> flags exonerated,
// R11 = XCD-local L2 transport w/ negotiated fallback.
// ============================================================================

typedef _Float16 f16;
typedef _Float16 f16x8 __attribute__((ext_vector_type(8)));
typedef float f32x4 __attribute__((ext_vector_type(4)));
typedef unsigned long long u64;

#define NB 256
#define NT_ 1024
#define NH 512
#define RING 16
#define SLOT (NB * NH)

__device__ __forceinline__ float sigm(float x)  { return 1.0f / (1.0f + __expf(-x)); }
__device__ __forceinline__ float tanhx(float x) { return 2.0f / (1.0f + __expf(-2.0f * x)) - 1.0f; }

// 8B agent-visible write-through store (verified R3/R4/R7 transport primitive)
__device__ __forceinline__ void st8(unsigned short* p, u64 v) {
  __hip_atomic_store((u64*)p, v, __ATOMIC_RELAXED, __HIP_MEMORY_SCOPE_AGENT);
}
__device__ __forceinline__ void stf(unsigned* p, unsigned v) {
  __hip_atomic_store(p, v, __ATOMIC_RELAXED, __HIP_MEMORY_SCOPE_AGENT);
}
__device__ __forceinline__ unsigned ldf(const unsigned* p) {
  return __hip_atomic_load(p, __ATOMIC_RELAXED, __HIP_MEMORY_SCOPE_AGENT);
}
// Poll until every lane's flag (per-lane address/threshold) passes.
__device__ __forceinline__ unsigned pollr(const unsigned* a, unsigned thr) {
  unsigned v;
  for (;;) {
    v = ldf(a);
    if (!~__ballot(v >= thr)) break;
    __builtin_amdgcn_s_sleep(1);
  }
  asm volatile("" ::: "memory");
  return v;
}

// flag line addressing: one 128B line (32 u32) per [chunk][slice][replica]
__device__ __forceinline__ unsigned* PFL(unsigned* pf, int c, int j, int r) {
  return pf + (((c * 16 + j) * 4) + r) * 32;
}
__device__ __forceinline__ unsigned* QFL(unsigned* qf, int c, int j, int r) {
  return qf + (((c * 32 + j) * 4) + r) * 32;
}

// ---------------------------------------------------------------------------
__global__ void prep_xT(const float* __restrict__ inp, float* __restrict__ xT) {
  int g = blockIdx.x * 256 + threadIdx.x;
  int t = g >> 8, b = g & 255;
  xT[t * NB + b] = inp[b * NT_ + t];
}

// ---------------------------------------------------------------------------
// fp32 -> fp16 weights in MFMA B-fragment order (verified R3; unchanged).
// L0 (Wh0): 16 slices x [nh<2][gate<4][kt<16][lane<64][j<8]; slice=65536 elems.
// L1 (Wx1, Wh1): 32 slices x [nh<2][jt<2][kt<16][lane<64][j<8]; slice=32768.
__global__ void prep_w(const float* __restrict__ Wh0,
                       const float* __restrict__ Wx1,
                       const float* __restrict__ Wh1,
                       f16* __restrict__ dst) {
  int g = blockIdx.x * 256 + threadIdx.x;   // 3 * 2^20 threads
  int mat = g >> 20;
  int r = g & 0xFFFFF;
  int j = r & 7, ln = (r >> 3) & 63, kt = (r >> 9) & 15;
  int cl = ln & 15, qd = ln >> 4;
  int k = kt * 32 + qd * 8 + j;
  size_t di; int gcol; const float* W;
  if (mat == 0) {
    int gt = (r >> 13) & 3, nh = (r >> 15) & 1, sl = (r >> 16) & 15;
    W = Wh0;
    gcol = gt * 512 + sl * 32 + nh * 16 + cl;
    di = (size_t)sl * 65536 + (((size_t)(nh * 4 + gt) * 16 + kt) * 64 + ln) * 8 + j;
  } else {
    int jt = (r >> 13) & 1, nh = (r >> 14) & 1, sl = (r >> 15) & 31;
    W = (mat == 1) ? Wx1 : Wh1;
    int gate = jt * 2 + (cl >> 3);
    gcol = gate * 512 + sl * 16 + nh * 8 + (cl & 7);
    di = (size_t)mat * 1048576 + (size_t)sl * 32768 +
         (((size_t)(nh * 2 + jt) * 16 + kt) * 64 + ln) * 8 + j;
  }
  dst[di] = (f16)W[(size_t)k * 2048 + gcol];
}

// ---------------------------------------------------------------------------
__global__ void reduce_out(const float* __restrict__ part8,
                           const float* __restrict__ bfp,
                           float* __restrict__ out) {
  int g = blockIdx.x * 256 + threadIdx.x;   // 262144 = b*1024+t
  float v = bfp[0];
#pragma unroll
  for (int j = 0; j < 8; ++j) v += part8[(size_t)j * (NB * NT_) + g];
  out[g] = v;
}

// ---------------------------------------------------------------------------
// h transport layouts (slice-major, per-WG-contiguous; R7-verified):
//   p[slot][c<4][sl<16][row<64][unit<32]  q[slot][c<4][sl<32][row<64][unit<16]
__global__ __launch_bounds__(256, 1) void lstm_main(
    const float* __restrict__ xT,       // [T][B]
    const f16*  __restrict__ wsl,       // tiled fp16 weights (6 MB)
    const float* __restrict__ wx0,      // [2048]
    const float* __restrict__ bias0,    // [2048]
    const float* __restrict__ bias1,    // [2048]
    const float* __restrict__ wf,       // [512]
    unsigned short* p_hi, unsigned short* p_lo,   // [RING][...] slice-major
    unsigned short* q_hi, unsigned short* q_lo,   // [RING][...] slice-major
    unsigned int* pf,                   // per-line flags [4c][16sl][4rep]x128B
    unsigned int* qf,                   // per-line flags [4c][32sl][4rep]x128B
    float* part8)                       // [8][B][T]
{
  extern __shared__ char smem[];
  const int tid = threadIdx.x;
  const int wv = tid >> 6, ln = tid & 63;
  const int qd = ln >> 4, cl = ln & 15;
  const int bx = blockIdx.x;
  const int r8 = bx & 7, idx = bx >> 3;
  const bool isL0 = !(r8 & 1);
  const int c = r8 >> 1;
  const int sl = idx;
  if (isL0 && idx >= 16) return;        // 64 spare WGs exit (uniform per WG)
  const float LO = 1.0f / 1024.0f;

  // ---- stage weight slice(s) into LDS (once) ----
  if (isL0) {
    const int4* s0 = (const int4*)wsl + (size_t)sl * 8192;           // 128 KB
    int4* d = (int4*)smem;
    for (int i = tid; i < 8192; i += 256) d[i] = s0[i];
  } else {
    const int4* s1 = (const int4*)wsl + 131072 + (size_t)sl * 4096;  // Wx1 64 KB
    const int4* s2 = (const int4*)wsl + 262144 + (size_t)sl * 4096;  // Wh1 64 KB
    int4* d = (int4*)smem;
    for (int i = tid; i < 4096; i += 256) { d[i] = s1[i]; d[4096 + i] = s2[i]; }
  }
  __syncthreads();

  if (isL0) {
    // ======== layer 0 ========
    // wave = (nh = wv>>1, rhalf = wv&1). 256 MFMA/wave/step, A in regs.
    const int nh = wv >> 1, rhalf = wv & 1;
    const int rb0 = c * 64 + rhalf * 32;                 // global batch row
    float wx0v[4], b0c[4];
#pragma unroll
    for (int g = 0; g < 4; ++g) {
      int gc = g * 512 + sl * 32 + nh * 16 + cl;
      wx0v[g] = wx0[gc];
      b0c[g] = bias0[gc];
    }
    float cst[2][4] = {{0.f,0.f,0.f,0.f},{0.f,0.f,0.f,0.f}};
    // combined step-start poll (per-wave): lanes 0-15 -> pf>=s, lanes 16-47
    // -> qf>=s-RING+1 (ring guard), lanes 48-63 -> pf mirror (alt replica).
    const bool isq = (ln >= 16 && ln < 48);
    const unsigned* pwa;
    if (ln < 16)      pwa = PFL(pf, c, ln, sl & 3);
    else if (ln < 48) pwa = QFL(qf, c, ln - 16, sl & 3);
    else              pwa = PFL(pf, c, ln - 48, (sl + 1) & 3);
    const f16x8* wl = (const f16x8*)smem;
    f16* sh  = (f16*)(smem + 131072);    // [64][32] hi stage (4 KB)
    f16* slo = sh + 2048;                // [64][32] lo stage (4 KB)

    for (int s = 0; s < NT_; ++s) {
      // ---- ring-epoch L1/L2 invalidate (addresses reused every 16 steps) ----
      if ((s & (RING - 1)) == 0 && s) {
        __syncthreads();
        if (wv == 0)
          asm volatile("buffer_inv sc1\n\ts_waitcnt vmcnt(0)" ::: "memory");
        __syncthreads();
      }
      const int slot_r = (s + RING - 1) & (RING - 1);   // h_{s-1}
      const int slot_w = s & (RING - 1);                // h_s
      // x prefetch — independent of flags, issue before the poll
      float4 xv[2];
#pragma unroll
      for (int rt = 0; rt < 2; ++rt)
        xv[rt] = *(const float4*)(xT + s * NB + rb0 + rt * 16 + qd * 4);
      if (s) {
        unsigned thr = isq ? (s >= RING ? (unsigned)(s - RING + 1) : 0u)
                           : (unsigned)s;
        pollr(pwa, thr);
      }
      // ---- preload ALL A fragments (h_{s-1} hi/lo) into registers ----
      // slice-major: slice kt holds units kt*32..+32
      f16x8 Ah[16][2], Al[16][2];
      {
        const f16* bh = (const f16*)p_hi + (size_t)slot_r * SLOT + (size_t)c * 32768 + qd * 8;
        const f16* bl = (const f16*)p_lo + (size_t)slot_r * SLOT + (size_t)c * 32768 + qd * 8;
#pragma unroll
        for (int kt = 0; kt < 16; ++kt)
#pragma unroll
          for (int rt = 0; rt < 2; ++rt) {
            int lr = rhalf * 32 + rt * 16 + cl;          // chunk-local row
            size_t off = (size_t)kt * 2048 + lr * 32;
            Ah[kt][rt] = *(const f16x8*)(bh + off);
            Al[kt][rt] = *(const f16x8*)(bl + off);
          }
      }
      f32x4 acc[4][2], accL[4][2];
#pragma unroll
      for (int g = 0; g < 4; ++g)
#pragma unroll
        for (int rt = 0; rt < 2; ++rt) {
          acc[g][rt] = (f32x4){0.f,0.f,0.f,0.f};
          accL[g][rt] = (f32x4){0.f,0.f,0.f,0.f};
        }
#pragma unroll
      for (int kt = 0; kt < 16; ++kt) {
#pragma unroll
        for (int g = 0; g < 4; ++g) {
          f16x8 bw = wl[((nh * 4 + g) * 16 + kt) * 64 + ln];
#pragma unroll
          for (int rt = 0; rt < 2; ++rt) {
            acc[g][rt]  = __builtin_amdgcn_mfma_f32_16x16x32_f16(Ah[kt][rt], bw, acc[g][rt], 0, 0, 0);
            accL[g][rt] = __builtin_amdgcn_mfma_f32_16x16x32_f16(Al[kt][rt], bw, accL[g][rt], 0, 0, 0);
          }
        }
      }
      // ---- epilogue -> LDS stage ----
#pragma unroll
      for (int rt = 0; rt < 2; ++rt)
#pragma unroll
        for (int e = 0; e < 4; ++e) {
          float xe = (e == 0) ? xv[rt].x : (e == 1) ? xv[rt].y : (e == 2) ? xv[rt].z : xv[rt].w;
          float gi = acc[0][rt][e] + accL[0][rt][e] * LO + xe * wx0v[0] + b0c[0];
          float gf = acc[1][rt][e] + accL[1][rt][e] * LO + xe * wx0v[1] + b0c[1];
          float gg = acc[2][rt][e] + accL[2][rt][e] * LO + xe * wx0v[2] + b0c[2];
          float go = acc[3][rt][e] + accL[3][rt][e] * LO + xe * wx0v[3] + b0c[3];
          float ii = sigm(gi), ff = sigm(gf), tg = tanhx(gg), oo = sigm(go);
          cst[rt][e] = ff * cst[rt][e] + ii * tg;
          float h = oo * tanhx(cst[rt][e]);
          f16 hh = (f16)h;
          int su = (rhalf * 32 + rt * 16 + qd * 4 + e) * 32 + nh * 16 + cl;
          sh[su]  = hh;
          slo[su] = (f16)((h - (float)hh) * 1024.0f);
        }
      __syncthreads();
      // ---- coop store: 2 x 4KB contiguous, 8B/lane, full-line coverage ----
      {
        unsigned short* bh = p_hi + (size_t)slot_w * SLOT + (size_t)c * 32768 + (size_t)sl * 2048;
        unsigned short* bl = p_lo + (size_t)slot_w * SLOT + (size_t)c * 32768 + (size_t)sl * 2048;
#pragma unroll
        for (int i = tid; i < 1024; i += 256) {
          int strm = i >> 9, pc = i & 511;               // 8B piece index
          const f16* src = (strm ? slo : sh) + pc * 4;
          st8((strm ? bl : bh) + pc * 4, *(const u64*)src);
        }
      }
      __syncthreads();   // all waves' stores vmcnt-drained at LLC before barrier
      if (tid < 4)       // 4 replica flags, each on its OWN 128B line
        stf(PFL(pf, c, sl, tid), (unsigned)(s + 1));
    }
  } else {
    // ======== layer 1: q_s = LSTM(p_s, q_{s-1}) ========
    int u = cl & 7, g01 = cl >> 3;
    const bool hiH = (cl < 8);
    float b1c0[2], b1c1[2], wfv[2];
#pragma unroll
    for (int nh = 0; nh < 2; ++nh) {
      int base = sl * 16 + nh * 8 + u;
      b1c0[nh] = bias1[g01 * 512 + base];
      b1c1[nh] = bias1[(2 + g01) * 512 + base];
      wfv[nh] = wf[base];
    }
    const int lr = wv * 16 + cl;                        // chunk-local row
    float cst[2][4] = {{0.f,0.f,0.f,0.f},{0.f,0.f,0.f,0.f}};
    // step-start combined read: lanes 0-31 qf (blocking, thr s), lanes 32-47
    // pf (advisory, thr s+1 -> fresh runahead gate), lanes 48-63 qf mirror.
    const unsigned* a_init;
    const bool isPf = (ln >= 32 && ln < 48);
    if (ln < 32)      a_init = QFL(qf, c, ln, sl & 3);
    else if (ln < 48) a_init = PFL(pf, c, ln - 32, sl & 3);
    else              a_init = QFL(qf, c, ln - 48, (sl + 1) & 3);
    // straggler pf poll addresses (all 64 lanes over 16 lines x replicas)
    const unsigned* ppf = PFL(pf, c, ln & 15, (sl + (ln >> 4)) & 3);
    const f16x8* wx_ = (const f16x8*)smem;
    const f16x8* wh_ = (const f16x8*)(smem + 65536);
    f16* sh  = (f16*)(smem + 131072);   // [64][16] hi stage (2 KB)
    f16* slo = sh + 1024;               // [64][16] lo stage (2 KB)

    for (int s = 0; s < NT_; ++s) {
      if ((s & (RING - 1)) == 0 && s) {
        __syncthreads();
        if (wv == 0)
          asm volatile("buffer_inv sc1\n\ts_waitcnt vmcnt(0)" ::: "memory");
        __syncthreads();
      }
      const int slot_r = (s + RING - 1) & (RING - 1);
      const int slot_w = s & (RING - 1);
      // blocking qf poll (peers done s-1) + advisory fresh pf view
      bool early = false;
      if (s) {
        unsigned thr_i = isPf ? (unsigned)(s + 1) : (unsigned)s;
        unsigned v = ldf(a_init);
        u64 bal = __ballot(v >= thr_i);
        while ((unsigned)bal != 0xFFFFFFFFu) {
          __builtin_amdgcn_s_sleep(1);
          v = ldf(a_init);
          bal = __ballot(v >= thr_i);
        }
        asm volatile("" ::: "memory");
        early = (((bal >> 32) & 0xFFFF) == 0xFFFF);
      }
      // preload q_{s-1} fragments (slice-major, 16-unit slices: unit
      // kt*32+qd*8 -> slice kt*2+(qd>>1), offset (qd&1)*8)
      const f16* aqh = (const f16*)q_hi + (size_t)slot_r * SLOT + (size_t)c * 32768 +
                       (qd >> 1) * 1024 + lr * 16 + (qd & 1) * 8;
      const f16* aql = (const f16*)q_lo + (size_t)slot_r * SLOT + (size_t)c * 32768 +
                       (qd >> 1) * 1024 + lr * 16 + (qd & 1) * 8;
      f16x8 Aq[16][2];
#pragma unroll
      for (int kt = 0; kt < 16; ++kt) {
        Aq[kt][0] = *(const f16x8*)(aqh + kt * 2048);
        Aq[kt][1] = *(const f16x8*)(aql + kt * 2048);
      }
      // runahead: fresh pf view showed L0 done step s -> issue p loads NOW
      const f16* aph = (const f16*)p_hi + (size_t)slot_w * SLOT + (size_t)c * 32768 +
                       lr * 32 + qd * 8;
      const f16* apl = (const f16*)p_lo + (size_t)slot_w * SLOT + (size_t)c * 32768 +
                       lr * 32 + qd * 8;
      f16x8 Ap[16][2];
      if (early) {
#pragma unroll
        for (int kt = 0; kt < 16; ++kt) {
          Ap[kt][0] = *(const f16x8*)(aph + kt * 2048);
          Ap[kt][1] = *(const f16x8*)(apl + kt * 2048);
        }
      }
      f32x4 acc[4], accL[4];
#pragma unroll
      for (int t4 = 0; t4 < 4; ++t4) {
        acc[t4] = (f32x4){0.f,0.f,0.f,0.f};
        accL[t4] = (f32x4){0.f,0.f,0.f,0.f};
      }
      // phase 1: q_{s-1} @ Wh1
#pragma unroll
      for (int kt = 0; kt < 16; ++kt) {
#pragma unroll
        for (int t4 = 0; t4 < 4; ++t4) {
          f16x8 bw = wh_[(t4 * 16 + kt) * 64 + ln];
          acc[t4]  = __builtin_amdgcn_mfma_f32_16x16x32_f16(Aq[kt][0], bw, acc[t4], 0, 0, 0);
          accL[t4] = __builtin_amdgcn_mfma_f32_16x16x32_f16(Aq[kt][1], bw, accL[t4], 0, 0, 0);
        }
      }
      if (!early) {
        pollr(ppf, (unsigned)(s + 1));
#pragma unroll
        for (int kt = 0; kt < 16; ++kt) {
          Ap[kt][0] = *(const f16x8*)(aph + kt * 2048);
          Ap[kt][1] = *(const f16x8*)(apl + kt * 2048);
        }
      }
      // phase 2: p_s @ Wx1
#pragma unroll
      for (int kt = 0; kt < 16; ++kt) {
#pragma unroll
        for (int t4 = 0; t4 < 4; ++t4) {
          f16x8 bw = wx_[(t4 * 16 + kt) * 64 + ln];
          acc[t4]  = __builtin_amdgcn_mfma_f32_16x16x32_f16(Ap[kt][0], bw, acc[t4], 0, 0, 0);
          accL[t4] = __builtin_amdgcn_mfma_f32_16x16x32_f16(Ap[kt][1], bw, accL[t4], 0, 0, 0);
        }
      }
      // ---- epilogue -> LDS stage ----
      float po[4];
#pragma unroll
      for (int e = 0; e < 4; ++e) {
        po[e] = 0.0f;
#pragma unroll
        for (int nh = 0; nh < 2; ++nh) {
          float v0 = acc[nh*2+0][e] + accL[nh*2+0][e] * LO + b1c0[nh];   // i / f
          float v1 = acc[nh*2+1][e] + accL[nh*2+1][e] * LO + b1c1[nh];   // g / o
          float w0 = __shfl_xor(v0, 8, 16);
          float w1 = __shfl_xor(v1, 8, 16);
          float gi = hiH ? v0 : w0;
          float gf = hiH ? w0 : v0;
          float gg = hiH ? v1 : w1;
          float go = hiH ? w1 : v1;
          float ii = sigm(gi), ff = sigm(gf), tg = tanhx(gg), oo = sigm(go);
          cst[nh][e] = ff * cst[nh][e] + ii * tg;
          float h = oo * tanhx(cst[nh][e]);
          int su = (wv * 16 + qd * 4 + e) * 16 + nh * 8 + u;
          if (hiH) {
            sh[su] = (f16)h;
          } else {
            f16 hh = (f16)h;
            slo[su] = (f16)((h - (float)hh) * 1024.0f);
          }
          po[e] += hiH ? wfv[nh] * h : 0.0f;
        }
      }
      __syncthreads();
      // ---- coop store: 2 x 2KB contiguous, 8B/lane, full-line coverage ----
      {
        unsigned short* bhq = q_hi + (size_t)slot_w * SLOT + (size_t)c * 32768 + (size_t)sl * 1024;
        unsigned short* blq = q_lo + (size_t)slot_w * SLOT + (size_t)c * 32768 + (size_t)sl * 1024;
#pragma unroll
        for (int i = tid; i < 512; i += 256) {
          int strm = i >> 8, pc = i & 255;               // 8B piece index
          const f16* src = (strm ? slo : sh) + pc * 4;
          st8((strm ? blq : bhq) + pc * 4, *(const u64*)src);
        }
      }
      __syncthreads();   // stores drained at LLC
      if (tid < 4)       // 4 replica flags, each on its OWN 128B line
        stf(QFL(qf, c, sl, tid), (unsigned)(s + 1));
      // deferred head-output reduce + atomic (off the q->q critical path)
#pragma unroll
      for (int e = 0; e < 4; ++e) {
        float r = po[e];
#pragma unroll
        for (int m = 1; m < 16; m <<= 1) r += __shfl_xor(r, m, 16);
        if (cl == 0)
          atomicAdd(part8 + (size_t)(sl & 7) * (NB * NT_) +
                        (size_t)(c * 64 + wv * 16 + qd * 4 + e) * NT_ + s, r);
      }
    }
  }
}

// ---------------------------------------------------------------------------
extern "C" void kernel_launch(void* const* d_in, const int* in_sizes, int n_in,
                              void* d_out, int out_size, void* d_ws, size_t ws_size,
                              hipStream_t stream) {
  (void)in_sizes; (void)n_in; (void)out_size; (void)ws_size;
  const float* inp = (const float*)d_in[0];
  const float* Wx0 = (const float*)d_in[1];
  const float* Wh0 = (const float*)d_in[2];
  const float* b0  = (const float*)d_in[3];
  const float* Wx1 = (const float*)d_in[4];
  const float* Wh1 = (const float*)d_in[5];
  const float* b1  = (const float*)d_in[6];
  const float* Wf  = (const float*)d_in[7];
  const float* bf  = (const float*)d_in[8];

  const size_t MB = 1u << 20;
  const size_t OFF_W    = 0;                 // 6 MiB tiled fp16 weights
  const size_t OFF_XT   = 6 * MB;            // 1 MiB
  const size_t OFF_PHI  = 7 * MB;            // 4 MiB (RING x 256 KB)
  const size_t OFF_PLO  = 11 * MB;
  const size_t OFF_QHI  = 15 * MB;
  const size_t OFF_QLO  = 19 * MB;
  const size_t OFF_PART = 23 * MB;           // 8 MiB
  const size_t OFF_CTR  = 31 * MB;           // flags: pf 32KB + qf 64KB

  char* ws = (char*)d_ws;
  f16* wsl = (f16*)(ws + OFF_W);
  float* xT = (float*)(ws + OFF_XT);
  unsigned short* phi = (unsigned short*)(ws + OFF_PHI);
  unsigned short* plo = (unsigned short*)(ws + OFF_PLO);
  unsigned short* qhi = (unsigned short*)(ws + OFF_QHI);
  unsigned short* qlo = (unsigned short*)(ws + OFF_QLO);
  float* part8 = (float*)(ws + OFF_PART);
  unsigned int* pfl = (unsigned int*)(ws + OFF_CTR);
  unsigned int* qfl = pfl + 8192;            // pf = 4*16*4 lines * 32 u32
  float* out = (float*)d_out;

  (void)hipFuncSetAttribute((const void*)lstm_main,
                            hipFuncAttributeMaxDynamicSharedMemorySize, 139264);

  // zero rings + partials + flags (contiguous; flags now 96 KB)
  (void)hipMemsetAsync(ws + OFF_PHI, 0, (OFF_CTR + 98304) - OFF_PHI, stream);

  prep_xT<<<1024, 256, 0, stream>>>(inp, xT);
  prep_w<<<12288, 256, 0, stream>>>(Wh0, Wx1, Wh1, wsl);

  lstm_main<<<256, 256, 139264, stream>>>(xT, wsl, Wx0, b0, b1, Wf,
                                          phi, plo, qhi, qlo, pfl, qfl, part8);

  reduce_out<<<1024, 256, 0, stream>>>(part8, bf, out);
}

// Round 7
// 9664.134 us; speedup vs baseline: 1.0561x; 1.0561x over previous
//
#include <hip/hip_runtime.h>

// ============================================================================
// 2-layer LSTM (B=256, T=1024, H=512, in=1) + linear head. fp32 in/out.
//
// R11 (from R10 @10.21ms): halve the per-step serial chain + use all 256 CUs.
// Evidence: R5/R9/R10 all neutral (pipelining, poll fan-in, flag lines);
// R7 -21% (store path). MfmaUtil 13% => ~1.3us compute of 10us period; rest
// is serial LLC hops + per-WG chain work. Levers that shorten the chain:
//  1. L0 restructured into L1's exact shape: 16-unit slices, 32 L0 WGs/chunk.
//     Per-WG: 64KB weights, A-loads 128KB with ZERO wave-dup (R8's goal,
//     without the spill: clone of the VGPR-safe L1 codepath, 128 MFMA/wave),
//     epilogue/stores halved. p transport = q layout (16-unit slice-major).
//  2. Grid 4x(32+32) = 256 WGs = all 256 CUs (64 idle CUs join the pull).
// Sync protocol FROZEN (R7/R10-verified): per-line flags (pf now 32 slices),
// lane-split polls, ring guard, epoch buffer_inv sc1, coop full-line st8
// stores, drain-then-flag. L1 runahead advisory covers all 32 pf flags.
// Math bit-identical: L0 gate assembly switches to L1's verified shfl-swap
// (same values & rounding). Expect absmax 6.1e-5.
// Predicted: chain-bound -> 6.5-8ms, MfmaUtil ~17-20, Occupancy ~12.5%;
// neutral -> agent-RT-pinned, R12 = XCD-local L2 transport w/ negotiation.
// ============================================================================

typedef _Float16 f16;
typedef _Float16 f16x8 __attribute__((ext_vector_type(8)));
typedef float f32x4 __attribute__((ext_vector_type(4)));
typedef unsigned long long u64;

#define NB 256
#define NT_ 1024
#define NH 512
#define RING 16
#define SLOT (NB * NH)

__device__ __forceinline__ float sigm(float x)  { return 1.0f / (1.0f + __expf(-x)); }
__device__ __forceinline__ float tanhx(float x) { return 2.0f / (1.0f + __expf(-2.0f * x)) - 1.0f; }

// 8B agent-visible write-through store (verified R3/R4/R7 transport primitive)
__device__ __forceinline__ void st8(unsigned short* p, u64 v) {
  __hip_atomic_store((u64*)p, v, __ATOMIC_RELAXED, __HIP_MEMORY_SCOPE_AGENT);
}
__device__ __forceinline__ void stf(unsigned* p, unsigned v) {
  __hip_atomic_store(p, v, __ATOMIC_RELAXED, __HIP_MEMORY_SCOPE_AGENT);
}
__device__ __forceinline__ unsigned ldf(const unsigned* p) {
  return __hip_atomic_load(p, __ATOMIC_RELAXED, __HIP_MEMORY_SCOPE_AGENT);
}
// Poll until every lane's flag (per-lane address/threshold) passes.
__device__ __forceinline__ unsigned pollr(const unsigned* a, unsigned thr) {
  unsigned v;
  for (;;) {
    v = ldf(a);
    if (!~__ballot(v >= thr)) break;
    __builtin_amdgcn_s_sleep(1);
  }
  asm volatile("" ::: "memory");
  return v;
}

// flag line addressing: one 128B line (32 u32) per [chunk][slice<32][replica]
__device__ __forceinline__ unsigned* PFL(unsigned* pf, int c, int j, int r) {
  return pf + (((c * 32 + j) * 4) + r) * 32;
}
__device__ __forceinline__ unsigned* QFL(unsigned* qf, int c, int j, int r) {
  return qf + (((c * 32 + j) * 4) + r) * 32;
}

// ---------------------------------------------------------------------------
__global__ void prep_xT(const float* __restrict__ inp, float* __restrict__ xT) {
  int g = blockIdx.x * 256 + threadIdx.x;
  int t = g >> 8, b = g & 255;
  xT[t * NB + b] = inp[b * NT_ + t];
}

// ---------------------------------------------------------------------------
// fp32 -> fp16 weights, UNIFIED tiling for all 3 matrices (L1's verified R3
// layout, now also for Wh0): 32 slices x [nh<2][jt<2][kt<16][lane<64][j<8];
// slice = 32768 elems. gcol = (jt*2+(cl>>3))*512 + sl*16 + nh*8 + (cl&7).
__global__ void prep_w(const float* __restrict__ Wh0,
                       const float* __restrict__ Wx1,
                       const float* __restrict__ Wh1,
                       f16* __restrict__ dst) {
  int g = blockIdx.x * 256 + threadIdx.x;   // 3 * 2^20 threads
  int mat = g >> 20;
  int r = g & 0xFFFFF;
  int j = r & 7, ln = (r >> 3) & 63, kt = (r >> 9) & 15;
  int cl = ln & 15, qd = ln >> 4;
  int k = kt * 32 + qd * 8 + j;
  int jt = (r >> 13) & 1, nh = (r >> 14) & 1, sl = (r >> 15) & 31;
  const float* W = (mat == 0) ? Wh0 : (mat == 1) ? Wx1 : Wh1;
  int gate = jt * 2 + (cl >> 3);
  int gcol = gate * 512 + sl * 16 + nh * 8 + (cl & 7);
  size_t di = (size_t)mat * 1048576 + (size_t)sl * 32768 +
              (((size_t)(nh * 2 + jt) * 16 + kt) * 64 + ln) * 8 + j;
  dst[di] = (f16)W[(size_t)k * 2048 + gcol];
}

// ---------------------------------------------------------------------------
__global__ void reduce_out(const float* __restrict__ part8,
                           const float* __restrict__ bfp,
                           float* __restrict__ out) {
  int g = blockIdx.x * 256 + threadIdx.x;   // 262144 = b*1024+t
  float v = bfp[0];
#pragma unroll
  for (int j = 0; j < 8; ++j) v += part8[(size_t)j * (NB * NT_) + g];
  out[g] = v;
}

// ---------------------------------------------------------------------------
// h transport layouts (slice-major, per-WG-contiguous), p NOW SAME AS q:
//   p[slot][c<4][sl<32][row<64][unit<16]  (elem = slot*131072 + c*32768
//   q[slot][c<4][sl<32][row<64][unit<16]   + sl*1024 + row*16 + unit)
__global__ __launch_bounds__(256, 1) void lstm_main(
    const float* __restrict__ xT,       // [T][B]
    const f16*  __restrict__ wsl,       // tiled fp16 weights (6 MB)
    const float* __restrict__ wx0,      // [2048]
    const float* __restrict__ bias0,    // [2048]
    const float* __restrict__ bias1,    // [2048]
    const float* __restrict__ wf,       // [512]
    unsigned short* p_hi, unsigned short* p_lo,   // [RING][...] slice-major
    unsigned short* q_hi, unsigned short* q_lo,   // [RING][...] slice-major
    unsigned int* pf,                   // per-line flags [4c][32sl][4rep]x128B
    unsigned int* qf,                   // per-line flags [4c][32sl][4rep]x128B
    float* part8)                       // [8][B][T]
{
  extern __shared__ char smem[];
  const int tid = threadIdx.x;
  const int wv = tid >> 6, ln = tid & 63;
  const int qd = ln >> 4, cl = ln & 15;
  const int bx = blockIdx.x;
  const int r8 = bx & 7, idx = bx >> 3;
  const bool isL0 = !(r8 & 1);
  const int c = r8 >> 1;
  const int sl = idx;                   // 0..31 for BOTH layers now
  const float LO = 1.0f / 1024.0f;
  const int u = cl & 7, g01 = cl >> 3;
  const bool hiH = (cl < 8);
  const int lr = wv * 16 + cl;          // chunk-local A row

  // ---- stage weight slice(s) into LDS (once) ----
  if (isL0) {
    const int4* s0 = (const int4*)wsl + (size_t)sl * 4096;           // 64 KB
    int4* d = (int4*)smem;
    for (int i = tid; i < 4096; i += 256) d[i] = s0[i];
  } else {
    const int4* s1 = (const int4*)wsl + 131072 + (size_t)sl * 4096;  // Wx1 64 KB
    const int4* s2 = (const int4*)wsl + 262144 + (size_t)sl * 4096;  // Wh1 64 KB
    int4* d = (int4*)smem;
    for (int i = tid; i < 4096; i += 256) { d[i] = s1[i]; d[4096 + i] = s2[i]; }
  }
  __syncthreads();

  if (isL0) {
    // ======== layer 0: p_s = LSTM(x_s, p_{s-1}) — L1-shaped ========
    float w0a[2], w0b[2], b0a[2], b0b[2];
#pragma unroll
    for (int nh = 0; nh < 2; ++nh) {
      int base = sl * 16 + nh * 8 + u;
      w0a[nh] = wx0[g01 * 512 + base];
      b0a[nh] = bias0[g01 * 512 + base];
      w0b[nh] = wx0[(2 + g01) * 512 + base];
      b0b[nh] = bias0[(2 + g01) * 512 + base];
    }
    float cst[2][4] = {{0.f,0.f,0.f,0.f},{0.f,0.f,0.f,0.f}};
    // step-start poll: lanes 0-31 -> pf[ln] >= s (peers done s-1),
    // lanes 32-63 -> qf[ln-32] >= s-RING+1 (ring-overwrite guard).
    const unsigned* pwa = (ln < 32) ? PFL(pf, c, ln, sl & 3)
                                    : QFL(qf, c, ln - 32, sl & 3);
    const f16x8* wl = (const f16x8*)smem;
    f16* sh  = (f16*)(smem + 65536);     // [64][16] hi stage (2 KB)
    f16* slo = sh + 1024;                // [64][16] lo stage (2 KB)

    for (int s = 0; s < NT_; ++s) {
      // ---- ring-epoch L1/L2 invalidate (addresses reused every 16 steps) ----
      if ((s & (RING - 1)) == 0 && s) {
        __syncthreads();
        if (wv == 0)
          asm volatile("buffer_inv sc1\n\ts_waitcnt vmcnt(0)" ::: "memory");
        __syncthreads();
      }
      const int slot_r = (s + RING - 1) & (RING - 1);   // h_{s-1}
      const int slot_w = s & (RING - 1);                // h_s
      // x prefetch — independent of flags, issue before the poll
      float4 xv = *(const float4*)(xT + s * NB + c * 64 + wv * 16 + qd * 4);
      if (s) {
        unsigned thr = (ln < 32) ? (unsigned)s
                                 : (s >= RING ? (unsigned)(s - RING + 1) : 0u);
        pollr(pwa, thr);
      }
      // ---- A fragments (p_{s-1} hi/lo), q-style 16-unit slice addressing ----
      const f16* ah = (const f16*)p_hi + (size_t)slot_r * SLOT + (size_t)c * 32768 +
                      (qd >> 1) * 1024 + lr * 16 + (qd & 1) * 8;
      const f16* al = (const f16*)p_lo + (size_t)slot_r * SLOT + (size_t)c * 32768 +
                      (qd >> 1) * 1024 + lr * 16 + (qd & 1) * 8;
      f16x8 Ah[16], Al[16];
#pragma unroll
      for (int kt = 0; kt < 16; ++kt) {
        Ah[kt] = *(const f16x8*)(ah + kt * 2048);
        Al[kt] = *(const f16x8*)(al + kt * 2048);
      }
      f32x4 acc[4], accL[4];
#pragma unroll
      for (int t4 = 0; t4 < 4; ++t4) {
        acc[t4] = (f32x4){0.f,0.f,0.f,0.f};
        accL[t4] = (f32x4){0.f,0.f,0.f,0.f};
      }
#pragma unroll
      for (int kt = 0; kt < 16; ++kt) {
#pragma unroll
        for (int t4 = 0; t4 < 4; ++t4) {                 // t4 = nh*2 + jt
          f16x8 bw = wl[(t4 * 16 + kt) * 64 + ln];
          acc[t4]  = __builtin_amdgcn_mfma_f32_16x16x32_f16(Ah[kt], bw, acc[t4], 0, 0, 0);
          accL[t4] = __builtin_amdgcn_mfma_f32_16x16x32_f16(Al[kt], bw, accL[t4], 0, 0, 0);
        }
      }
      // ---- epilogue (L1-style shfl-swap gate assembly) -> LDS stage ----
#pragma unroll
      for (int e = 0; e < 4; ++e) {
        float xe = (e == 0) ? xv.x : (e == 1) ? xv.y : (e == 2) ? xv.z : xv.w;
        int r = wv * 16 + qd * 4 + e;
#pragma unroll
        for (int nh = 0; nh < 2; ++nh) {
          float v0 = acc[nh*2+0][e] + accL[nh*2+0][e] * LO + xe * w0a[nh] + b0a[nh]; // i/f
          float v1 = acc[nh*2+1][e] + accL[nh*2+1][e] * LO + xe * w0b[nh] + b0b[nh]; // g/o
          float w0 = __shfl_xor(v0, 8, 16);
          float w1 = __shfl_xor(v1, 8, 16);
          float gi = hiH ? v0 : w0;
          float gf = hiH ? w0 : v0;
          float gg = hiH ? v1 : w1;
          float go = hiH ? w1 : v1;
          float ii = sigm(gi), ff = sigm(gf), tg = tanhx(gg), oo = sigm(go);
          cst[nh][e] = ff * cst[nh][e] + ii * tg;
          float h = oo * tanhx(cst[nh][e]);
          int su = r * 16 + nh * 8 + u;
          if (hiH) {
            sh[su] = (f16)h;
          } else {
            f16 hh = (f16)h;
            slo[su] = (f16)((h - (float)hh) * 1024.0f);
          }
        }
      }
      __syncthreads();
      // ---- coop store: 2 x 2KB contiguous, 8B/lane, full-line coverage ----
      {
        unsigned short* bh = p_hi + (size_t)slot_w * SLOT + (size_t)c * 32768 + (size_t)sl * 1024;
        unsigned short* bl = p_lo + (size_t)slot_w * SLOT + (size_t)c * 32768 + (size_t)sl * 1024;
#pragma unroll
        for (int i = tid; i < 512; i += 256) {
          int strm = i >> 8, pc = i & 255;               // 8B piece index
          const f16* src = (strm ? slo : sh) + pc * 4;
          st8((strm ? bl : bh) + pc * 4, *(const u64*)src);
        }
      }
      __syncthreads();   // all waves' stores vmcnt-drained at LLC before barrier
      if (tid < 4)       // 4 replica flags, each on its OWN 128B line
        stf(PFL(pf, c, sl, tid), (unsigned)(s + 1));
    }
  } else {
    // ======== layer 1: q_s = LSTM(p_s, q_{s-1}) ========
    float b1c0[2], b1c1[2], wfv[2];
#pragma unroll
    for (int nh = 0; nh < 2; ++nh) {
      int base = sl * 16 + nh * 8 + u;
      b1c0[nh] = bias1[g01 * 512 + base];
      b1c1[nh] = bias1[(2 + g01) * 512 + base];
      wfv[nh] = wf[base];
    }
    float cst[2][4] = {{0.f,0.f,0.f,0.f},{0.f,0.f,0.f,0.f}};
    // step-start combined read: lanes 0-31 qf (blocking, thr s),
    // lanes 32-63 pf (advisory, thr s+1 -> fresh full-coverage runahead gate).
    const unsigned* a_init = (ln < 32) ? QFL(qf, c, ln, sl & 3)
                                       : PFL(pf, c, ln - 32, sl & 3);
    // straggler pf poll addresses (64 lanes over 32 lines x replicas)
    const unsigned* ppf = PFL(pf, c, ln & 31, (sl + (ln >> 5)) & 3);
    const f16x8* wx_ = (const f16x8*)smem;
    const f16x8* wh_ = (const f16x8*)(smem + 65536);
    f16* sh  = (f16*)(smem + 131072);   // [64][16] hi stage (2 KB)
    f16* slo = sh + 1024;               // [64][16] lo stage (2 KB)

    for (int s = 0; s < NT_; ++s) {
      if ((s & (RING - 1)) == 0 && s) {
        __syncthreads();
        if (wv == 0)
          asm volatile("buffer_inv sc1\n\ts_waitcnt vmcnt(0)" ::: "memory");
        __syncthreads();
      }
      const int slot_r = (s + RING - 1) & (RING - 1);
      const int slot_w = s & (RING - 1);
      // blocking qf poll (peers done s-1) + advisory fresh pf view
      bool early = false;
      if (s) {
        unsigned thr_i = (ln < 32) ? (unsigned)s : (unsigned)(s + 1);
        unsigned v = ldf(a_init);
        u64 bal = __ballot(v >= thr_i);
        while ((unsigned)bal != 0xFFFFFFFFu) {
          __builtin_amdgcn_s_sleep(1);
          v = ldf(a_init);
          bal = __ballot(v >= thr_i);
        }
        asm volatile("" ::: "memory");
        early = ((unsigned)(bal >> 32) == 0xFFFFFFFFu);
      }
      // preload q_{s-1} fragments (16-unit slice addressing)
      const f16* aqh = (const f16*)q_hi + (size_t)slot_r * SLOT + (size_t)c * 32768 +
                       (qd >> 1) * 1024 + lr * 16 + (qd & 1) * 8;
      const f16* aql = (const f16*)q_lo + (size_t)slot_r * SLOT + (size_t)c * 32768 +
                       (qd >> 1) * 1024 + lr * 16 + (qd & 1) * 8;
      f16x8 Aq[16][2];
#pragma unroll
      for (int kt = 0; kt < 16; ++kt) {
        Aq[kt][0] = *(const f16x8*)(aqh + kt * 2048);
        Aq[kt][1] = *(const f16x8*)(aql + kt * 2048);
      }
      // runahead: fresh pf view showed L0 done step s -> issue p loads NOW
      const f16* aph = (const f16*)p_hi + (size_t)slot_w * SLOT + (size_t)c * 32768 +
                       (qd >> 1) * 1024 + lr * 16 + (qd & 1) * 8;
      const f16* apl = (const f16*)p_lo + (size_t)slot_w * SLOT + (size_t)c * 32768 +
                       (qd >> 1) * 1024 + lr * 16 + (qd & 1) * 8;
      f16x8 Ap[16][2];
      if (early) {
#pragma unroll
        for (int kt = 0; kt < 16; ++kt) {
          Ap[kt][0] = *(const f16x8*)(aph + kt * 2048);
          Ap[kt][1] = *(const f16x8*)(apl + kt * 2048);
        }
      }
      f32x4 acc[4], accL[4];
#pragma unroll
      for (int t4 = 0; t4 < 4; ++t4) {
        acc[t4] = (f32x4){0.f,0.f,0.f,0.f};
        accL[t4] = (f32x4){0.f,0.f,0.f,0.f};
      }
      // phase 1: q_{s-1} @ Wh1
#pragma unroll
      for (int kt = 0; kt < 16; ++kt) {
#pragma unroll
        for (int t4 = 0; t4 < 4; ++t4) {
          f16x8 bw = wh_[(t4 * 16 + kt) * 64 + ln];
          acc[t4]  = __builtin_amdgcn_mfma_f32_16x16x32_f16(Aq[kt][0], bw, acc[t4], 0, 0, 0);
          accL[t4] = __builtin_amdgcn_mfma_f32_16x16x32_f16(Aq[kt][1], bw, accL[t4], 0, 0, 0);
        }
      }
      if (!early) {
        pollr(ppf, (unsigned)(s + 1));
#pragma unroll
        for (int kt = 0; kt < 16; ++kt) {
          Ap[kt][0] = *(const f16x8*)(aph + kt * 2048);
          Ap[kt][1] = *(const f16x8*)(apl + kt * 2048);
        }
      }
      // phase 2: p_s @ Wx1
#pragma unroll
      for (int kt = 0; kt < 16; ++kt) {
#pragma unroll
        for (int t4 = 0; t4 < 4; ++t4) {
          f16x8 bw = wx_[(t4 * 16 + kt) * 64 + ln];
          acc[t4]  = __builtin_amdgcn_mfma_f32_16x16x32_f16(Ap[kt][0], bw, acc[t4], 0, 0, 0);
          accL[t4] = __builtin_amdgcn_mfma_f32_16x16x32_f16(Ap[kt][1], bw, accL[t4], 0, 0, 0);
        }
      }
      // ---- epilogue -> LDS stage ----
      float po[4];
#pragma unroll
      for (int e = 0; e < 4; ++e) {
        po[e] = 0.0f;
#pragma unroll
        for (int nh = 0; nh < 2; ++nh) {
          float v0 = acc[nh*2+0][e] + accL[nh*2+0][e] * LO + b1c0[nh];   // i / f
          float v1 = acc[nh*2+1][e] + accL[nh*2+1][e] * LO + b1c1[nh];   // g / o
          float w0 = __shfl_xor(v0, 8, 16);
          float w1 = __shfl_xor(v1, 8, 16);
          float gi = hiH ? v0 : w0;
          float gf = hiH ? w0 : v0;
          float gg = hiH ? v1 : w1;
          float go = hiH ? w1 : v1;
          float ii = sigm(gi), ff = sigm(gf), tg = tanhx(gg), oo = sigm(go);
          cst[nh][e] = ff * cst[nh][e] + ii * tg;
          float h = oo * tanhx(cst[nh][e]);
          int su = (wv * 16 + qd * 4 + e) * 16 + nh * 8 + u;
          if (hiH) {
            sh[su] = (f16)h;
          } else {
            f16 hh = (f16)h;
            slo[su] = (f16)((h - (float)hh) * 1024.0f);
          }
          po[e] += hiH ? wfv[nh] * h : 0.0f;
        }
      }
      __syncthreads();
      // ---- coop store: 2 x 2KB contiguous, 8B/lane, full-line coverage ----
      {
        unsigned short* bhq = q_hi + (size_t)slot_w * SLOT + (size_t)c * 32768 + (size_t)sl * 1024;
        unsigned short* blq = q_lo + (size_t)slot_w * SLOT + (size_t)c * 32768 + (size_t)sl * 1024;
#pragma unroll
        for (int i = tid; i < 512; i += 256) {
          int strm = i >> 8, pc = i & 255;               // 8B piece index
          const f16* src = (strm ? slo : sh) + pc * 4;
          st8((strm ? blq : bhq) + pc * 4, *(const u64*)src);
        }
      }
      __syncthreads();   // stores drained at LLC
      if (tid < 4)       // 4 replica flags, each on its OWN 128B line
        stf(QFL(qf, c, sl, tid), (unsigned)(s + 1));
      // deferred head-output reduce + atomic (off the q->q critical path)
#pragma unroll
      for (int e = 0; e < 4; ++e) {
        float r = po[e];
#pragma unroll
        for (int m = 1; m < 16; m <<= 1) r += __shfl_xor(r, m, 16);
        if (cl == 0)
          atomicAdd(part8 + (size_t)(sl & 7) * (NB * NT_) +
                        (size_t)(c * 64 + wv * 16 + qd * 4 + e) * NT_ + s, r);
      }
    }
  }
}

// ---------------------------------------------------------------------------
extern "C" void kernel_launch(void* const* d_in, const int* in_sizes, int n_in,
                              void* d_out, int out_size, void* d_ws, size_t ws_size,
                              hipStream_t stream) {
  (void)in_sizes; (void)n_in; (void)out_size; (void)ws_size;
  const float* inp = (const float*)d_in[0];
  const float* Wx0 = (const float*)d_in[1];
  const float* Wh0 = (const float*)d_in[2];
  const float* b0  = (const float*)d_in[3];
  const float* Wx1 = (const float*)d_in[4];
  const float* Wh1 = (const float*)d_in[5];
  const float* b1  = (const float*)d_in[6];
  const float* Wf  = (const float*)d_in[7];
  const float* bf  = (const float*)d_in[8];

  const size_t MB = 1u << 20;
  const size_t OFF_W    = 0;                 // 6 MiB tiled fp16 weights
  const size_t OFF_XT   = 6 * MB;            // 1 MiB
  const size_t OFF_PHI  = 7 * MB;            // 4 MiB (RING x 256 KB)
  const size_t OFF_PLO  = 11 * MB;
  const size_t OFF_QHI  = 15 * MB;
  const size_t OFF_QLO  = 19 * MB;
  const size_t OFF_PART = 23 * MB;           // 8 MiB
  const size_t OFF_CTR  = 31 * MB;           // flags: pf 64KB + qf 64KB

  char* ws = (char*)d_ws;
  f16* wsl = (f16*)(ws + OFF_W);
  float* xT = (float*)(ws + OFF_XT);
  unsigned short* phi = (unsigned short*)(ws + OFF_PHI);
  unsigned short* plo = (unsigned short*)(ws + OFF_PLO);
  unsigned short* qhi = (unsigned short*)(ws + OFF_QHI);
  unsigned short* qlo = (unsigned short*)(ws + OFF_QLO);
  float* part8 = (float*)(ws + OFF_PART);
  unsigned int* pfl = (unsigned int*)(ws + OFF_CTR);
  unsigned int* qfl = pfl + 16384;           // pf = 512 lines * 32 u32
  float* out = (float*)d_out;

  (void)hipFuncSetAttribute((const void*)lstm_main,
                            hipFuncAttributeMaxDynamicSharedMemorySize, 135168);

  // zero rings + partials + flags (contiguous; flags 128 KB)
  (void)hipMemsetAsync(ws + OFF_PHI, 0, (OFF_CTR + 131072) - OFF_PHI, stream);

  prep_xT<<<1024, 256, 0, stream>>>(inp, xT);
  prep_w<<<12288, 256, 0, stream>>>(Wh0, Wx1, Wh1, wsl);

  lstm_main<<<256, 256, 135168, stream>>>(xT, wsl, Wx0, b0, b1, Wf,
                                          phi, plo, qhi, qlo, pfl, qfl, part8);

  reduce_out<<<1024, 256, 0, stream>>>(part8, bf, out);
}